// Round 4
// baseline (731.200 us; speedup 1.0000x reference)
//
#include <hip/hip_runtime.h>
#include <hip/hip_bf16.h>
#include <cstdint>
#include <cstddef>

// Problem constants
#define BB 2
#define SS 2048
#define DD 4096
#define HH 32
#define KVH 8
#define DH 128
#define KVD 1024
#define SCALE 0.08838834764831845f   // DH^-0.5
// SCALE * log2(e): folded into Q so softmax runs in exp2 domain
#define QSC 0.1275178745225f

typedef __attribute__((ext_vector_type(8))) short short8;
typedef __attribute__((ext_vector_type(4))) float f32x4;

typedef __attribute__((address_space(1))) void GV;
typedef __attribute__((address_space(3))) void LV;

__device__ __forceinline__ void async16(const void* g, void* l) {
  __builtin_amdgcn_global_load_lds((GV*)g, (LV*)l, 16, 0, 0);
}

__device__ __forceinline__ unsigned short f2bf(float x) {
  union { float f; uint32_t u; } v; v.f = x;
  uint32_t r = (v.u + 0x7fffu + ((v.u >> 16) & 1u)) >> 16;
  return (unsigned short)r;
}
__device__ __forceinline__ float bf2f(unsigned short b) {
  union { uint32_t u; float f; } v; v.u = ((uint32_t)b) << 16; return v.f;
}
__device__ __forceinline__ f32x4 mfma16(short8 a, short8 b, f32x4 c) {
  return __builtin_amdgcn_mfma_f32_16x16x32_bf16(a, b, c, 0, 0, 0);
}

// ---------------- cast fp32 -> bf16 (straight) ----------------
__global__ __launch_bounds__(256) void cast_bf16_kernel(
    const float* __restrict__ in, unsigned short* __restrict__ out, int n4) {
  int i = blockIdx.x * 256 + threadIdx.x;
  if (i >= n4) return;
  float4 v = ((const float4*)in)[i];
  ushort4 o;
  o.x = f2bf(v.x); o.y = f2bf(v.y); o.z = f2bf(v.z); o.w = f2bf(v.w);
  ((ushort4*)out)[i] = o;
}

// ---------------- cast + transpose: (R x C) fp32 -> (C x R) bf16 ----------------
__global__ __launch_bounds__(256) void transpose_cast_kernel(
    const float* __restrict__ in, unsigned short* __restrict__ out, int R, int C) {
  __shared__ unsigned short tile[32][33];
  const int tx = threadIdx.x, ty = threadIdx.y;       // block (32,8)
  const int c0 = blockIdx.x * 32, r0 = blockIdx.y * 32;
  for (int i = ty; i < 32; i += 8)
    tile[i][tx] = f2bf(in[(size_t)(r0 + i) * C + c0 + tx]);
  __syncthreads();
  for (int i = ty; i < 32; i += 8)
    out[(size_t)(c0 + i) * R + r0 + tx] = tile[tx][i];
}

// ---------------- V transpose: qkv[b*S+s][5120 + kvh*128 + d] -> vo[(b,kvh,d,s)] ----
__global__ __launch_bounds__(256) void transpose_v_kernel(
    const unsigned short* __restrict__ qkv, unsigned short* __restrict__ vo) {
  __shared__ unsigned short tile[32][33];
  const int s0 = blockIdx.x * 32, d0 = blockIdx.y * 32;
  const int b = blockIdx.z >> 3, kvh = blockIdx.z & 7;
  const int tx = threadIdx.x, ty = threadIdx.y;       // block (32,8)
  const unsigned short* ip = qkv + 5120 + (size_t)kvh * 128 + d0 + tx;
  for (int i = ty; i < 32; i += 8)
    tile[i][tx] = ip[(size_t)(b * SS + s0 + i) * 6144];
  __syncthreads();
  unsigned short* op = vo + (size_t)(b * KVH + kvh) * DH * SS + s0 + tx;
  for (int i = ty; i < 32; i += 8)
    op[(size_t)(d0 + i) * SS] = tile[tx][i];
}

// ---------------- GEMM: C[M,N] = A[M,K] * Bt[N,K]^T  (bf16 in, fp32 acc) ----------
// 256x256 tile, BK=64, 8 waves (2M x 4N), 128 KiB LDS double-buffer.
// K-loop with OVERLAPPED LDS reads: all 24 fragment ds_read_b128 of tile t are
// issued early (12 during tile t-1's last MFMA quadrant, 12 at tile start) and
// each MFMA quadrant is gated by a COUNTED lgkmcnt (12/8/0) instead of a full
// drain -- the LDS unit runs underneath the MFMA pipe. 3 barriers per K-tile.
// Quadrant order: Q1=A0xB0, Q2=A0xB1, Q3=A1xB1, Q4=A1xB0. B0/B1 register
// storage swaps parity each tile (loop unrolled x2) so next-tile early reads
// land in dead registers. Staging (t+2, same-parity buffer) keeps the old
// discipline: each half-tile slot is re-staged only after the barrier following
// the lgkm gate that covers its last reader. vmcnt(6) once per tile (before
// barrier #3) proves tile t+1 landed block-wide before its reads issue.
// LDS swizzle: granule g of row r at phys g ^ (r&7), applied on the global
// source side (gload_lds LDS dst is lane-linear); ds_read granule
// (ks*4+quad) ^ (l16&7) -> conflict-free (measured 0 conflicts).
// [VERIFIED round 2: 213us, MfmaUtil 41%, 0 bank conflicts -- restored
//  verbatim after round-3's BK=32 rewrite failed to bench.]

#define GBAR()  asm volatile("s_barrier" ::: "memory")
#define WAIT_LGKM(N)                                               \
  do {                                                             \
    asm volatile("s_waitcnt lgkmcnt(" #N ")" ::: "memory");        \
    __builtin_amdgcn_sched_barrier(0);                             \
  } while (0)
#define WAIT_VM(N)                                                 \
  do {                                                             \
    asm volatile("s_waitcnt vmcnt(" #N ")" ::: "memory");          \
    __builtin_amdgcn_sched_barrier(0);                             \
  } while (0)

// stage one A half-tile (rows with bit6==mh) of K-tile tt into buffer p
#define STG_A(tt, mh, p)                                                         \
  do {                                                                           \
    async16(Abase + (size_t)(arb0 + (mh) * 64) * K + (size_t)(tt) * 64 + loffA,  \
            ldsA + (p) * 16384 + (arb0 + (mh) * 64) * 64);                       \
    async16(Abase + (size_t)(arb1 + (mh) * 64) * K + (size_t)(tt) * 64 + loffA,  \
            ldsA + (p) * 16384 + (arb1 + (mh) * 64) * 64);                       \
  } while (0)
// stage one B half-tile (rows with bit5==nh) of K-tile tt into buffer p
#define STG_B(tt, nh, p)                                                         \
  do {                                                                           \
    async16(Bbase + (size_t)(brb0 + (nh) * 32) * K + (size_t)(tt) * 64 + loffB,  \
            ldsB + (p) * 16384 + (brb0 + (nh) * 32) * 64);                       \
    async16(Bbase + (size_t)(brb1 + (nh) * 32) * K + (size_t)(tt) * 64 + loffB,  \
            ldsB + (p) * 16384 + (brb1 + (nh) * 32) * 64);                       \
  } while (0)

// 12 reads: A-frags 0..3 (both k-steps), B-frags 0..1 into B0R
#define ISSUE_A0_B0(P, B0R)                                          \
  {                                                                  \
    const unsigned short* pA_ = ldsA + (P) * 16384 + arow;           \
    const unsigned short* pB_ = ldsB + (P) * 16384 + brow;           \
    A0[0][0] = *(const short8*)(pA_ + 0 * 1024 + pg0);               \
    A0[0][1] = *(const short8*)(pA_ + 0 * 1024 + pg1);               \
    A0[1][0] = *(const short8*)(pA_ + 1 * 1024 + pg0);               \
    A0[1][1] = *(const short8*)(pA_ + 1 * 1024 + pg1);               \
    A0[2][0] = *(const short8*)(pA_ + 2 * 1024 + pg0);               \
    A0[2][1] = *(const short8*)(pA_ + 2 * 1024 + pg1);               \
    A0[3][0] = *(const short8*)(pA_ + 3 * 1024 + pg0);               \
    A0[3][1] = *(const short8*)(pA_ + 3 * 1024 + pg1);               \
    B0R[0][0] = *(const short8*)(pB_ + 0 * 1024 + pg0);              \
    B0R[0][1] = *(const short8*)(pB_ + 0 * 1024 + pg1);              \
    B0R[1][0] = *(const short8*)(pB_ + 1 * 1024 + pg0);              \
    B0R[1][1] = *(const short8*)(pB_ + 1 * 1024 + pg1);              \
  }

// 12 reads: B-frags 2..3 into B1R, A-frags 4..7 (both k-steps)
#define ISSUE_B1_A1(P, B1R)                                          \
  {                                                                  \
    const unsigned short* pA_ = ldsA + (P) * 16384 + arow;           \
    const unsigned short* pB_ = ldsB + (P) * 16384 + brow;           \
    B1R[0][0] = *(const short8*)(pB_ + 2 * 1024 + pg0);              \
    B1R[0][1] = *(const short8*)(pB_ + 2 * 1024 + pg1);              \
    B1R[1][0] = *(const short8*)(pB_ + 3 * 1024 + pg0);              \
    B1R[1][1] = *(const short8*)(pB_ + 3 * 1024 + pg1);              \
    A1[0][0] = *(const short8*)(pA_ + 4 * 1024 + pg0);               \
    A1[0][1] = *(const short8*)(pA_ + 4 * 1024 + pg1);               \
    A1[1][0] = *(const short8*)(pA_ + 5 * 1024 + pg0);               \
    A1[1][1] = *(const short8*)(pA_ + 5 * 1024 + pg1);               \
    A1[2][0] = *(const short8*)(pA_ + 6 * 1024 + pg0);               \
    A1[2][1] = *(const short8*)(pA_ + 6 * 1024 + pg1);               \
    A1[3][0] = *(const short8*)(pA_ + 7 * 1024 + pg0);               \
    A1[3][1] = *(const short8*)(pA_ + 7 * 1024 + pg1);               \
  }

#define QMFMA(I0, J0, AR, BR)                                               \
  _Pragma("unroll") for (int i_ = 0; i_ < 4; ++i_)                          \
  _Pragma("unroll") for (int j_ = 0; j_ < 2; ++j_) {                        \
    acc[(I0) + i_][(J0) + j_] =                                             \
        mfma16(AR[i_][0], BR[j_][0], acc[(I0) + i_][(J0) + j_]);            \
    acc[(I0) + i_][(J0) + j_] =                                             \
        mfma16(AR[i_][1], BR[j_][1], acc[(I0) + i_][(J0) + j_]);            \
  }

// One K-tile. Entry: 12 reads (A0,B0R of tile T) in flight; tile T landed
// block-wide; vm: tile T+1's 8 stage-loads in flight.
#define BODY(T, P, B0R, B1R)                                                \
  {                                                                         \
    const bool st_ = ((T) + 2 < nt);                                        \
    ISSUE_B1_A1(P, B1R);                                                    \
    WAIT_LGKM(12);                       /* A0,B0 ready */                  \
    __builtin_amdgcn_s_setprio(1);                                          \
    QMFMA(0, 0, A0, B0R);                                                   \
    __builtin_amdgcn_s_setprio(0);                                          \
    __builtin_amdgcn_sched_barrier(0);                                      \
    GBAR();                              /* #1: A-h0,B-h0 reads done */     \
    if (st_) { STG_A((T) + 2, 0, P); STG_B((T) + 2, 0, P); }                \
    WAIT_LGKM(8);                        /* B1 ready */                     \
    __builtin_amdgcn_s_setprio(1);                                          \
    QMFMA(0, 2, A0, B1R);                                                   \
    __builtin_amdgcn_s_setprio(0);                                          \
    __builtin_amdgcn_sched_barrier(0);                                      \
    GBAR();                              /* #2: B-h1 reads done */          \
    if (st_) STG_B((T) + 2, 1, P);                                          \
    WAIT_LGKM(0);                        /* A1 ready */                     \
    __builtin_amdgcn_s_setprio(1);                                          \
    QMFMA(4, 2, A1, B1R);                                                   \
    __builtin_amdgcn_s_setprio(0);                                          \
    __builtin_amdgcn_sched_barrier(0);                                      \
    if (st_) { WAIT_VM(6); } else { WAIT_VM(0); }  /* tile T+1 landed */    \
    GBAR();                              /* #3: block-wide */               \
    if (st_) STG_A((T) + 2, 1, P);                                          \
    if ((T) + 1 < nt) ISSUE_A0_B0((P) ^ 1, B1R); /* early reads, dead regs */\
    __builtin_amdgcn_sched_barrier(0);                                      \
    __builtin_amdgcn_s_setprio(1);                                          \
    QMFMA(4, 0, A1, B0R);                                                   \
    __builtin_amdgcn_s_setprio(0);                                          \
    __builtin_amdgcn_sched_barrier(0);                                      \
  }

template <typename OutT>
__global__ __launch_bounds__(512, 2) void gemm_bt(
    const unsigned short* __restrict__ A, const unsigned short* __restrict__ Bt,
    OutT* __restrict__ C, int M, int N, int K) {
  __shared__ __align__(16) unsigned short lds[65536];   // 128 KiB
  unsigned short* ldsA = lds;           // [2][256][64]
  unsigned short* ldsB = lds + 32768;   // [2][256][64]
  const int tid = threadIdx.x;
  const int wave = __builtin_amdgcn_readfirstlane(tid >> 6);  // SGPR-pinned
  const int lane = tid & 63, quad = lane >> 4, l16 = lane & 15;

  // bijective XCD-aware block swizzle over linear grid
  const int tn_n = N >> 8;
  const int nwg = (int)gridDim.x;
  const int q = nwg >> 3, r = nwg & 7;
  const int xcd = (int)blockIdx.x & 7, lin = (int)blockIdx.x >> 3;
  const int wg = (xcd < r) ? xcd * (q + 1) + lin
                           : r * (q + 1) + (xcd - r) * q + lin;
  const int m0 = (wg / tn_n) * 256, n0 = (wg % tn_n) * 256;

  // ---- staging address prep (wave-uniform row blocks in SGPR, lane part in 1 VGPR)
  const int blk0 = wave * 2, blk1 = blk0 + 1;                 // 8-row blocks
  const int arb0 = ((blk0 & 7) << 3) + ((blk0 >> 3) << 7);    // + mh*64
  const int arb1 = ((blk1 & 7) << 3) + ((blk1 >> 3) << 7);
  const int brb0 = ((blk0 >> 2) << 6) + ((blk0 & 3) << 3);    // + nh*32
  const int brb1 = ((blk1 >> 2) << 6) + ((blk1 & 3) << 3);
  const int lrow = lane >> 3;
  const int loffA = lrow * K + (((lane & 7) ^ lrow) << 3);    // lane part (VGPR)
  const int loffB = loffA;
  const unsigned short* Abase = A + (size_t)m0 * K;
  const unsigned short* Bbase = Bt + (size_t)n0 * K;

  // ---- fragment-read bases
  const int pg0 = ((quad) ^ (l16 & 7)) * 8;        // ks=0 granule (elems)
  const int pg1 = ((quad + 4) ^ (l16 & 7)) * 8;    // ks=1 granule
  const int arow = ((wave >> 2) * 128 + l16) * 64;
  const int brow = ((wave & 3) * 64 + l16) * 64;

  f32x4 acc[8][4] = {};
  short8 A0[4][2], A1[4][2], Bx[2][2], By[2][2];

  const int nt = K >> 6;
  // ---- prologue: tiles 0 and 1 fully staged; tile0 guaranteed, tile1 in flight
  STG_A(0, 0, 0); STG_B(0, 0, 0); STG_B(0, 1, 0); STG_A(0, 1, 0);
  STG_A(1, 0, 1); STG_B(1, 0, 1); STG_B(1, 1, 1); STG_A(1, 1, 1);
  WAIT_VM(8);
  GBAR();
  ISSUE_A0_B0(0, Bx);   // tile 0: A0 + B0 reads in flight

  for (int t = 0; t < nt; t += 2) {
    BODY(t, 0, Bx, By);
    BODY(t + 1, 1, By, Bx);
  }

  // ---- epilogue: acc[mf][nf] -> C
  const int cm = m0 + (wave >> 2) * 128 + quad * 4;
  const int cn = n0 + (wave & 3) * 64 + l16;
#pragma unroll
  for (int i = 0; i < 8; ++i)
#pragma unroll
    for (int j = 0; j < 4; ++j)
#pragma unroll
      for (int rr = 0; rr < 4; ++rr) {
        const size_t idx = (size_t)(cm + i * 16 + rr) * N + (cn + j * 16);
        if constexpr (sizeof(OutT) == 4) C[idx] = acc[i][j][rr];
        else                             C[idx] = (OutT)f2bf(acc[i][j][rr]);
      }
}

#undef STG_A
#undef STG_B
#undef ISSUE_A0_B0
#undef ISSUE_B1_A1
#undef QMFMA
#undef BODY

// ---------------- RMSNorm + RoPE (Q,K only; V handled by transpose_v) --------
// Q output pre-scaled by QSC = SCALE*log2(e) so softmax runs in exp2 domain.
__global__ __launch_bounds__(256) void rmsnorm_rope_kernel(
    const unsigned short* __restrict__ qkv,
    const float* __restrict__ q_scale, const float* __restrict__ k_scale,
    const float* __restrict__ cosc, const float* __restrict__ sinc,
    unsigned short* __restrict__ qo,   // (B,H,S,DH)
    unsigned short* __restrict__ ko)   // (B,KVH,S,DH)
{
  const int row = blockIdx.x;              // b*S + s
  const int b = row >> 11, s = row & 2047;
  const int tid = threadIdx.x;
  const unsigned short* qr = qkv + (size_t)row * 6144;
  // vectorized sum of squares
  short8 qv0 = *(const short8*)&qr[tid * 8];
  short8 qv1 = *(const short8*)&qr[2048 + tid * 8];
  ushort4 kv = *(const ushort4*)&qr[4096 + tid * 4];
  float sq = 0.f, sk = 0.f;
#pragma unroll
  for (int e = 0; e < 8; e++) {
    float a = bf2f((unsigned short)qv0[e]); sq += a * a;
    float c = bf2f((unsigned short)qv1[e]); sq += c * c;
  }
  float kf[4];
#pragma unroll
  for (int e = 0; e < 4; e++) {
    kf[e] = bf2f(((const unsigned short*)&kv)[e]); sk += kf[e] * kf[e];
  }
#pragma unroll
  for (int off = 32; off; off >>= 1) {
    sq += __shfl_down(sq, off, 64);
    sk += __shfl_down(sk, off, 64);
  }
  __shared__ float redq[4], redk[4];
  if ((tid & 63) == 0) { redq[tid >> 6] = sq; redk[tid >> 6] = sk; }
  __syncthreads();
  sq = redq[0] + redq[1] + redq[2] + redq[3];
  sk = redk[0] + redk[1] + redk[2] + redk[3];
  const float rq = rsqrtf(sq * (1.f / 4096.f) + 1e-6f);
  const float rk = rsqrtf(sk * (1.f / 1024.f) + 1e-6f);
  const float* cp = cosc + (size_t)row * 128;
  const float* sp = sinc + (size_t)row * 128;
  // Q: two chunks of 8 contiguous elems per thread
#pragma unroll
  for (int it = 0; it < 2; it++) {
    const int c = it * 2048 + tid * 8;
    const int d = c & 127, hh = c >> 7;
    short8 v8 = it ? qv1 : qv0;
    short8 p8 = *(const short8*)&qr[c ^ 64];   // rotate-half partner granule
    const float sgn = (d < 64) ? -1.f : 1.f;
    ushort o8[8];
#pragma unroll
    for (int e = 0; e < 8; e++) {
      float v = bf2f((unsigned short)v8[e]) * rq * q_scale[c + e];
      float p = bf2f((unsigned short)p8[e]) * rq * q_scale[(c ^ 64) + e];
      o8[e] = f2bf((v * cp[d + e] + sgn * p * sp[d + e]) * QSC);
    }
    *(uint4*)&qo[((size_t)(b * HH + hh) * SS + s) * DH + d] = *(const uint4*)o8;
  }
  // K: 4 contiguous elems per thread
  {
    const int c = tid * 4;
    const int d = c & 127, hh = c >> 7;
    ushort4 p4 = *(const ushort4*)&qr[4096 + (c ^ 64)];
    const float sgn = (d < 64) ? -1.f : 1.f;
    ushort o4[4];
#pragma unroll
    for (int e = 0; e < 4; e++) {
      float v = kf[e] * rk * k_scale[c + e];
      float p = bf2f(((const unsigned short*)&p4)[e]) * rk * k_scale[(c ^ 64) + e];
      o4[e] = f2bf(v * cp[d + e] + sgn * p * sp[d + e]);
    }
    *(uint2*)&ko[((size_t)(b * KVH + hh) * SS + s) * DH + d] = *(const uint2*)o4;
  }
}

// ---------------- Flash attention: S^T form, 128 q-rows/block, 64-key tiles -----
// NEW this round: double-buffered K/V (2-phase prefetch, T3-minimum pattern):
// tile t+1's 8 global_load_lds issue BEFORE tile t's compute; one
// __syncthreads per tile (its implicit vmcnt(0)+lgkmcnt(0) drain proves t+1
// landed AND all waves consumed buf[t&1] reads -- WAR-safe for t+1's stage of
// buf[t^1]). Plus s_setprio(1) around QK and PV MFMA clusters (m191: attn
// blocks are independent, setprio regime applies). LDS 48->80 KiB, still
// 2 blocks/CU at 160 KiB.
#define STAGE_KV(KT, PB)                                                        \
  _Pragma("unroll") for (int j = 0; j < 4; j++) {                               \
    async16(Kg + (size_t)(KT) * 8192 + bK[j], &Ks[PB][(wave * 4 + j) * 512]);   \
    async16(Vg + (size_t)(KT) * 64 + bV[j], &Vs[PB][(wave * 4 + j) * 512]);     \
  }

__global__ __launch_bounds__(256, 2) void flash_attn(
    const unsigned short* __restrict__ Q,   // (B,H,S,DH), pre-scaled by QSC
    const unsigned short* __restrict__ Kr,  // (B,KVH,S,DH)
    const unsigned short* __restrict__ Vt,  // (B,KVH,DH,S)
    unsigned short* __restrict__ O)         // (B,S,H*DH)
{
  __shared__ __align__(16) unsigned short Ks[2][8192];  // 2x(64 keys x 128 d) swizzled
  __shared__ __align__(16) unsigned short Vs[2][8192];  // 2x(128 d x 64 keys) swizzled
  __shared__ __align__(16) unsigned int   Ps[4][1024];  // per-wave P [32 m][64 k] bf16 (swizzled)
  const int tid = threadIdx.x, wave = tid >> 6, lane = tid & 63;
  const int quad = lane >> 4, l16 = lane & 15;
  const int bh = blockIdx.x, b = bh >> 5, h = bh & 31;
  const int kvh = h >> 2;
  const int qbase = ((int)gridDim.y - 1 - (int)blockIdx.y) * 128;  // heavy-first
  const unsigned short* Qb = Q + (size_t)(b * HH + h) * SS * DH;
  short8 qf[2][4];
#pragma unroll
  for (int mi = 0; mi < 2; mi++) {
    const unsigned short* Qp = Qb + (size_t)(qbase + mi * 64 + wave * 16 + l16) * DH + quad * 8;
#pragma unroll
    for (int c = 0; c < 4; c++) qf[mi][c] = *(const short8*)(Qp + c * 32);
  }
  const unsigned short* Kg = Kr + (size_t)(b * KVH + kvh) * SS * DH;
  const unsigned short* Vg = Vt + (size_t)(b * KVH + kvh) * DH * SS;
  int bK[4], bV[4];
#pragma unroll
  for (int j = 0; j < 4; j++) {
    const int kk = wave * 16 + j * 4 + quad;
    const int gd = l16 ^ ((j * 4 + quad) & 15);
    bK[j] = kk * 128 + gd * 8;
    const int dd = (wave * 4 + j) * 8 + (lane >> 3);
    const int gk = (lane & 7) ^ ((lane >> 3) & 7);
    bV[j] = dd * 2048 + gk * 8;
  }
  f32x4 o[2][8] = {};
  float m_i[2] = {-1e30f, -1e30f}, l_i[2] = {0.f, 0.f};
  const int ndiag = qbase >> 6;
  const int nkt = ndiag + 2;

  STAGE_KV(0, 0);
  __syncthreads();               // implicit vmcnt(0): tile 0 landed
  for (int kt = 0; kt < nkt; kt++) {
    const int pb = kt & 1;
    if (kt + 1 < nkt) { STAGE_KV(kt + 1, pb ^ 1); }   // prefetch under compute
    const unsigned short* Kb = &Ks[pb][0];
    const unsigned short* Vb = &Vs[pb][0];
    const int k0 = kt * 64;
    f32x4 st[4][2] = {};
    __builtin_amdgcn_s_setprio(1);
#pragma unroll
    for (int km = 0; km < 4; km++) {
      const unsigned short* krow = Kb + (km * 16 + l16) * 128;
#pragma unroll
      for (int c = 0; c < 4; c++) {
        short8 kf = *(const short8*)(krow + (((c * 4 + quad) ^ l16) * 8));
        st[km][0] = mfma16(kf, qf[0][c], st[km][0]);
        st[km][1] = mfma16(kf, qf[1][c], st[km][1]);
      }
    }
    __builtin_amdgcn_s_setprio(0);
    const bool mtile = (kt >= ndiag);
    float alpha[2];
#pragma unroll
    for (int mi = 0; mi < 2; mi++) {
      if (mtile) {
        const int qg = qbase + mi * 64 + wave * 16 + l16;
#pragma unroll
        for (int km = 0; km < 4; km++)
#pragma unroll
          for (int r = 0; r < 4; r++)
            if (k0 + km * 16 + quad * 4 + r > qg) st[km][mi][r] = -1e4f;
      }
      float tmax = -3e38f;
#pragma unroll
      for (int km = 0; km < 4; km++)
#pragma unroll
        for (int r = 0; r < 4; r++) tmax = fmaxf(tmax, st[km][mi][r]);
      tmax = fmaxf(tmax, __shfl_xor(tmax, 16, 64));
      tmax = fmaxf(tmax, __shfl_xor(tmax, 32, 64));
      const float mn = fmaxf(m_i[mi], tmax);
      alpha[mi] = __builtin_amdgcn_exp2f(m_i[mi] - mn);
      m_i[mi] = mn;
      float rs = 0.f;
#pragma unroll
      for (int km = 0; km < 4; km++)
#pragma unroll
        for (int r = 0; r < 4; r++) {
          float e = __builtin_amdgcn_exp2f(st[km][mi][r] - mn);
          st[km][mi][r] = e;
          rs += e;
        }
      rs += __shfl_xor(rs, 16, 64);
      rs += __shfl_xor(rs, 32, 64);
      l_i[mi] = l_i[mi] * alpha[mi] + rs;
      unsigned int* pw = &Ps[wave][(mi * 16 + l16) * 32 + (quad & 1) * 2];
#pragma unroll
      for (int km = 0; km < 4; km++) {
        const int g = (km * 2 + (quad >> 1)) ^ (l16 & 7);
        float e0 = st[km][mi][0], e1 = st[km][mi][1], e2 = st[km][mi][2], e3 = st[km][mi][3];
        pw[g * 4]     = __builtin_amdgcn_perm(__builtin_bit_cast(unsigned int, e1),
                                              __builtin_bit_cast(unsigned int, e0), 0x07060302u);
        pw[g * 4 + 1] = __builtin_amdgcn_perm(__builtin_bit_cast(unsigned int, e3),
                                              __builtin_bit_cast(unsigned int, e2), 0x07060302u);
      }
    }
    if (__any((alpha[0] != 1.f) || (alpha[1] != 1.f))) {
#pragma unroll
      for (int mi = 0; mi < 2; mi++) {
        float ar[4];
#pragma unroll
        for (int r = 0; r < 4; r++)
          ar[r] = __shfl(alpha[mi], (lane & 48) + quad * 4 + r, 64);
#pragma unroll
        for (int f = 0; f < 8; f++)
#pragma unroll
          for (int r = 0; r < 4; r++) o[mi][f][r] *= ar[r];
      }
    }
#pragma unroll
    for (int kc = 0; kc < 2; kc++) {
      short8 pa[2];
#pragma unroll
      for (int mi = 0; mi < 2; mi++) {
        const int g = (kc * 4 + quad) ^ (l16 & 7);
        uint4 pv4 = *(const uint4*)&Ps[wave][(mi * 16 + l16) * 32 + g * 4];
        pa[mi] = __builtin_bit_cast(short8, pv4);
      }
      __builtin_amdgcn_s_setprio(1);
#pragma unroll
      for (int f = 0; f < 8; f++) {
        const int d = f * 16 + l16;
        short8 vf = *(const short8*)(Vb + d * 64 + (((kc * 4 + quad) ^ (l16 & 7)) * 8));
        o[0][f] = mfma16(pa[0], vf, o[0][f]);
        o[1][f] = mfma16(pa[1], vf, o[1][f]);
      }
      __builtin_amdgcn_s_setprio(0);
    }
    __syncthreads();             // drains vmcnt (tile kt+1 landed) + rendezvous
  }
  float il[2][4];
#pragma unroll
  for (int mi = 0; mi < 2; mi++)
#pragma unroll
    for (int r = 0; r < 4; r++) {
      float lv = __shfl(l_i[mi], (lane & 48) + quad * 4 + r, 64);
      il[mi][r] = 1.f / lv;
    }
#pragma unroll
  for (int mi = 0; mi < 2; mi++) {
    unsigned short* Op = O + (size_t)(b * SS + qbase + mi * 64 + wave * 16 + quad * 4) * DD + h * DH + l16;
#pragma unroll
    for (int f = 0; f < 8; f++)
#pragma unroll
      for (int r = 0; r < 4; r++)
        Op[(size_t)r * DD + f * 16] = f2bf(o[mi][f][r] * il[mi][r]);
  }
}
#undef STAGE_KV

// -------------------------------------------------------------------------------
extern "C" void kernel_launch(void* const* d_in, const int* in_sizes, int n_in,
                              void* d_out, int out_size, void* d_ws, size_t ws_size,
                              hipStream_t stream) {
  const float* hs      = (const float*)d_in[0];
  const float* wqkv    = (const float*)d_in[1];
  const float* wout    = (const float*)d_in[2];
  const float* q_scale = (const float*)d_in[3];
  const float* k_scale = (const float*)d_in[4];
  const float* cosc    = (const float*)d_in[5];
  const float* sinc    = (const float*)d_in[6];
  // d_in[7] = attention_mask: causal, recomputed from indices — not read.
  float* out = (float*)d_out;

  unsigned short* ws = (unsigned short*)d_ws;
  unsigned short* wqkvT = ws;                        // 6144*4096 = 25165824
  unsigned short* woutT = wqkvT + 25165824;          // 4096*4096 = 16777216
  unsigned short* hsb   = woutT + 16777216;          // 4096*4096 = 16777216
  unsigned short* qkv   = hsb + 16777216;            // 4096*6144 = 25165824
  unsigned short* qrope = wqkvT;                     // alias (wqkvT dead after GEMM1)
  unsigned short* krope = wqkvT + 16777216;
  unsigned short* vT    = wqkvT + 16777216 + 4194304;
  unsigned short* attno = hsb;                       // alias (hsb dead after GEMM1)

  cast_bf16_kernel<<<16384, 256, 0, stream>>>(hs, hsb, 4194304);
  transpose_cast_kernel<<<dim3(192, 128), dim3(32, 8), 0, stream>>>(wqkv, wqkvT, 4096, 6144);
  transpose_cast_kernel<<<dim3(128, 128), dim3(32, 8), 0, stream>>>(wout, woutT, 4096, 4096);
  gemm_bt<unsigned short><<<dim3(384), 512, 0, stream>>>(hsb, wqkvT, qkv, 4096, 6144, 4096);
  rmsnorm_rope_kernel<<<4096, 256, 0, stream>>>(qkv, q_scale, k_scale, cosc, sinc,
                                                qrope, krope);
  transpose_v_kernel<<<dim3(64, 4, 16), dim3(32, 8), 0, stream>>>(qkv, vT);
  flash_attn<<<dim3(64, 16), 256, 0, stream>>>(qrope, krope, vT, attno);
  gemm_bt<float><<<dim3(256), 512, 0, stream>>>(attno, woutT, out, 4096, 4096, 4096);
}

// Round 5
// 714.587 us; speedup vs baseline: 1.0232x; 1.0232x over previous
//
#include <hip/hip_runtime.h>
#include <hip/hip_bf16.h>
#include <cstdint>
#include <cstddef>

// Problem constants
#define BB 2
#define SS 2048
#define DD 4096
#define HH 32
#define KVH 8
#define DH 128
#define KVD 1024
#define SCALE 0.08838834764831845f   // DH^-0.5
// SCALE * log2(e): folded into Q so softmax runs in exp2 domain
#define QSC 0.1275178745225f

typedef __attribute__((ext_vector_type(8))) short short8;
typedef __attribute__((ext_vector_type(4))) float f32x4;

typedef __attribute__((address_space(1))) void GV;
typedef __attribute__((address_space(3))) void LV;

__device__ __forceinline__ void async16(const void* g, void* l) {
  __builtin_amdgcn_global_load_lds((GV*)g, (LV*)l, 16, 0, 0);
}

__device__ __forceinline__ unsigned short f2bf(float x) {
  union { float f; uint32_t u; } v; v.f = x;
  uint32_t r = (v.u + 0x7fffu + ((v.u >> 16) & 1u)) >> 16;
  return (unsigned short)r;
}
__device__ __forceinline__ float bf2f(unsigned short b) {
  union { uint32_t u; float f; } v; v.u = ((uint32_t)b) << 16; return v.f;
}
__device__ __forceinline__ f32x4 mfma16(short8 a, short8 b, f32x4 c) {
  return __builtin_amdgcn_mfma_f32_16x16x32_bf16(a, b, c, 0, 0, 0);
}

// ---------------- cast fp32 -> bf16 (straight) ----------------
__global__ __launch_bounds__(256) void cast_bf16_kernel(
    const float* __restrict__ in, unsigned short* __restrict__ out, int n4) {
  int i = blockIdx.x * 256 + threadIdx.x;
  if (i >= n4) return;
  float4 v = ((const float4*)in)[i];
  ushort4 o;
  o.x = f2bf(v.x); o.y = f2bf(v.y); o.z = f2bf(v.z); o.w = f2bf(v.w);
  ((ushort4*)out)[i] = o;
}

// ---------------- cast + transpose: (R x C) fp32 -> (C x R) bf16 ----------------
__global__ __launch_bounds__(256) void transpose_cast_kernel(
    const float* __restrict__ in, unsigned short* __restrict__ out, int R, int C) {
  __shared__ unsigned short tile[32][33];
  const int tx = threadIdx.x, ty = threadIdx.y;       // block (32,8)
  const int c0 = blockIdx.x * 32, r0 = blockIdx.y * 32;
  for (int i = ty; i < 32; i += 8)
    tile[i][tx] = f2bf(in[(size_t)(r0 + i) * C + c0 + tx]);
  __syncthreads();
  for (int i = ty; i < 32; i += 8)
    out[(size_t)(c0 + i) * R + r0 + tx] = tile[tx][i];
}

// ---------------- V transpose: qkv[b*S+s][5120 + kvh*128 + d] -> vo[(b,kvh,d,s)] ----
__global__ __launch_bounds__(256) void transpose_v_kernel(
    const unsigned short* __restrict__ qkv, unsigned short* __restrict__ vo) {
  __shared__ unsigned short tile[32][33];
  const int s0 = blockIdx.x * 32, d0 = blockIdx.y * 32;
  const int b = blockIdx.z >> 3, kvh = blockIdx.z & 7;
  const int tx = threadIdx.x, ty = threadIdx.y;       // block (32,8)
  const unsigned short* ip = qkv + 5120 + (size_t)kvh * 128 + d0 + tx;
  for (int i = ty; i < 32; i += 8)
    tile[i][tx] = ip[(size_t)(b * SS + s0 + i) * 6144];
  __syncthreads();
  unsigned short* op = vo + (size_t)(b * KVH + kvh) * DH * SS + s0 + tx;
  for (int i = ty; i < 32; i += 8)
    op[(size_t)(d0 + i) * SS] = tile[tx][i];
}

// ---------------- GEMM: C[M,N] = A[M,K] * Bt[N,K]^T  (bf16 in, fp32 acc) ----------
// 256xBN tile (BN=256 or 192), BK=64, 8 waves (2M x 4N), LDS double-buffer.
// VERIFIED round-2 schedule, parametrized on BN only (packing fix: GEMM1 at
// BN=192 -> grid 512 = exactly 2 full rounds on 256 CUs; BN=256's 384-block
// grid wasted 25% on the tail round. Per-tile counts shift by the T4 formula:
//   BN=256: loads/tile 8, gates lgkm 12/8/0, vm 6, prologue vm 8, NF=4
//   BN=192: loads/tile 7, gates lgkm 10/8/0, vm 5, prologue vm 7, NF=3
// All 24 (BN=256) / 22 (BN=192) fragment ds_read_b128 of tile t issue early
// (half during tile t-1's last MFMA quadrant, half at tile start); each MFMA
// quadrant gated by COUNTED lgkmcnt. 3 barriers per K-tile. Staging (t+2,
// same-parity buffer): each half-tile slot re-staged only after the barrier
// following the lgkm gate that covers its last reader. vmcnt(6/5) once per
// tile proves t+1 landed block-wide before its reads issue.
// LDS swizzle: granule g of row r at phys g ^ (r&7), applied on the global
// source side (gload_lds LDS dst is lane-linear); ds_read granule
// (ks*4+quad) ^ (l16&7) -> conflict-free (measured 0 conflicts).

#define GBAR()  asm volatile("s_barrier" ::: "memory")
#define WAIT_LGKM(N)                                               \
  do {                                                             \
    asm volatile("s_waitcnt lgkmcnt(" #N ")" ::: "memory");        \
    __builtin_amdgcn_sched_barrier(0);                             \
  } while (0)
#define WAIT_VM(N)                                                 \
  do {                                                             \
    asm volatile("s_waitcnt vmcnt(" #N ")" ::: "memory");          \
    __builtin_amdgcn_sched_barrier(0);                             \
  } while (0)

// stage one A half-tile (rows with bit6==mh) of K-tile tt into buffer p (2 loads)
#define STG_A(tt, mh, p)                                                         \
  do {                                                                           \
    async16(Abase + (size_t)(arb0 + (mh) * 64) * K + (size_t)(tt) * 64 + loff,   \
            ldsA + (p) * 16384 + (arb0 + (mh) * 64) * 64);                       \
    async16(Abase + (size_t)(arb1 + (mh) * 64) * K + (size_t)(tt) * 64 + loff,   \
            ldsA + (p) * 16384 + (arb1 + (mh) * 64) * 64);                       \
  } while (0)
// stage B half0 (rows read by nf0-1) of K-tile tt into buffer p (2 loads)
#define STG_BH0(tt, p)                                                           \
  do {                                                                           \
    async16(Bbase + (size_t)bh0r0 * K + (size_t)(tt) * 64 + loff,                \
            ldsB + (p) * BST + bh0r0 * 64);                                      \
    async16(Bbase + (size_t)bh0r1 * K + (size_t)(tt) * 64 + loff,                \
            ldsB + (p) * BST + bh0r1 * 64);                                      \
  } while (0)
// stage B half1 (rows read by nf2[,nf3]) of K-tile tt into buffer p (2 or 1 loads)
#define STG_BH1(tt, p)                                                           \
  do {                                                                           \
    async16(Bbase + (size_t)bh1r0 * K + (size_t)(tt) * 64 + loff,                \
            ldsB + (p) * BST + bh1r0 * 64);                                      \
    if constexpr (BN == 256)                                                     \
      async16(Bbase + (size_t)bh1r1 * K + (size_t)(tt) * 64 + loff,              \
              ldsB + (p) * BST + bh1r1 * 64);                                    \
  } while (0)

// 12 reads: A-frags 0..3 (both k-steps), B-frags 0..1 into B0R
#define ISSUE_A0_B0(P, B0R)                                          \
  {                                                                  \
    const unsigned short* pA_ = ldsA + (P) * 16384 + arow;           \
    const unsigned short* pB_ = ldsB + (P) * BST + brow;             \
    A0[0][0] = *(const short8*)(pA_ + 0 * 1024 + pg0);               \
    A0[0][1] = *(const short8*)(pA_ + 0 * 1024 + pg1);               \
    A0[1][0] = *(const short8*)(pA_ + 1 * 1024 + pg0);               \
    A0[1][1] = *(const short8*)(pA_ + 1 * 1024 + pg1);               \
    A0[2][0] = *(const short8*)(pA_ + 2 * 1024 + pg0);               \
    A0[2][1] = *(const short8*)(pA_ + 2 * 1024 + pg1);               \
    A0[3][0] = *(const short8*)(pA_ + 3 * 1024 + pg0);               \
    A0[3][1] = *(const short8*)(pA_ + 3 * 1024 + pg1);               \
    B0R[0][0] = *(const short8*)(pB_ + 0 * 1024 + pg0);              \
    B0R[0][1] = *(const short8*)(pB_ + 0 * 1024 + pg1);              \
    B0R[1][0] = *(const short8*)(pB_ + 1 * 1024 + pg0);              \
    B0R[1][1] = *(const short8*)(pB_ + 1 * 1024 + pg1);              \
  }

// B-frags 2..NF-1 into B1R, then A-frags 4..7 (both k-steps): 12 or 10 reads
#define ISSUE_B1_A1(P, B1R)                                          \
  {                                                                  \
    const unsigned short* pA_ = ldsA + (P) * 16384 + arow;           \
    const unsigned short* pB_ = ldsB + (P) * BST + brow;             \
    B1R[0][0] = *(const short8*)(pB_ + 2 * 1024 + pg0);              \
    B1R[0][1] = *(const short8*)(pB_ + 2 * 1024 + pg1);              \
    if constexpr (BN == 256) {                                       \
      B1R[1][0] = *(const short8*)(pB_ + 3 * 1024 + pg0);            \
      B1R[1][1] = *(const short8*)(pB_ + 3 * 1024 + pg1);            \
    }                                                                \
    A1[0][0] = *(const short8*)(pA_ + 4 * 1024 + pg0);               \
    A1[0][1] = *(const short8*)(pA_ + 4 * 1024 + pg1);               \
    A1[1][0] = *(const short8*)(pA_ + 5 * 1024 + pg0);               \
    A1[1][1] = *(const short8*)(pA_ + 5 * 1024 + pg1);               \
    A1[2][0] = *(const short8*)(pA_ + 6 * 1024 + pg0);               \
    A1[2][1] = *(const short8*)(pA_ + 6 * 1024 + pg1);               \
    A1[3][0] = *(const short8*)(pA_ + 7 * 1024 + pg0);               \
    A1[3][1] = *(const short8*)(pA_ + 7 * 1024 + pg1);               \
  }

#define QMFMA(I0, J0, JN, AR, BR)                                           \
  _Pragma("unroll") for (int i_ = 0; i_ < 4; ++i_)                          \
  _Pragma("unroll") for (int j_ = 0; j_ < (JN); ++j_) {                     \
    acc[(I0) + i_][(J0) + j_] =                                             \
        mfma16(AR[i_][0], BR[j_][0], acc[(I0) + i_][(J0) + j_]);            \
    acc[(I0) + i_][(J0) + j_] =                                             \
        mfma16(AR[i_][1], BR[j_][1], acc[(I0) + i_][(J0) + j_]);            \
  }

// One K-tile. Entry: 12 reads (A0,B0R of tile T) in flight; tile T landed
// block-wide; vm: tile T+1's stage-loads (8 or 7) in flight.
#define BODY(T, P, B0R, B1R)                                                \
  {                                                                         \
    const bool st_ = ((T) + 2 < nt);                                        \
    ISSUE_B1_A1(P, B1R);                                                    \
    if constexpr (BN == 256) { WAIT_LGKM(12); } else { WAIT_LGKM(10); }     \
    __builtin_amdgcn_s_setprio(1);                                          \
    QMFMA(0, 0, 2, A0, B0R);                                                \
    __builtin_amdgcn_s_setprio(0);                                          \
    __builtin_amdgcn_sched_barrier(0);                                      \
    GBAR();                              /* #1: A-h0,B-h0 reads done */     \
    if (st_) { STG_A((T) + 2, 0, P); STG_BH0((T) + 2, P); }                 \
    WAIT_LGKM(8);                        /* B1 ready */                     \
    __builtin_amdgcn_s_setprio(1);                                          \
    QMFMA(0, 2, NF - 2, A0, B1R);                                           \
    __builtin_amdgcn_s_setprio(0);                                          \
    __builtin_amdgcn_sched_barrier(0);                                      \
    GBAR();                              /* #2: B-h1 reads done */          \
    if (st_) STG_BH1((T) + 2, P);                                           \
    WAIT_LGKM(0);                        /* A1 ready */                     \
    __builtin_amdgcn_s_setprio(1);                                          \
    QMFMA(4, 2, NF - 2, A1, B1R);                                           \
    __builtin_amdgcn_s_setprio(0);                                          \
    __builtin_amdgcn_sched_barrier(0);                                      \
    if (st_) {                                                              \
      if constexpr (BN == 256) { WAIT_VM(6); } else { WAIT_VM(5); }         \
    } else { WAIT_VM(0); }               /* tile T+1 landed */              \
    GBAR();                              /* #3: block-wide */               \
    if (st_) STG_A((T) + 2, 1, P);                                          \
    if ((T) + 1 < nt) ISSUE_A0_B0((P) ^ 1, B1R); /* early reads, dead regs */\
    __builtin_amdgcn_sched_barrier(0);                                      \
    __builtin_amdgcn_s_setprio(1);                                          \
    QMFMA(4, 0, 2, A1, B0R);                                                \
    __builtin_amdgcn_s_setprio(0);                                          \
    __builtin_amdgcn_sched_barrier(0);                                      \
  }

template <int BN, typename OutT>
__global__ __launch_bounds__(512, 2) void gemm_bt(
    const unsigned short* __restrict__ A, const unsigned short* __restrict__ Bt,
    OutT* __restrict__ C, int M, int N, int K) {
  constexpr int NF = BN / 64;                 // N-frags per wave (4 or 3)
  constexpr int BST = BN * 64;                // B buffer stride (shorts)
  __shared__ __align__(16) unsigned short lds[32768 + 2 * BST];
  unsigned short* ldsA = lds;                 // [2][256][64]
  unsigned short* ldsB = lds + 32768;         // [2][BN][64]
  const int tid = threadIdx.x;
  const int wave = __builtin_amdgcn_readfirstlane(tid >> 6);  // SGPR-pinned
  const int lane = tid & 63, quad = lane >> 4, l16 = lane & 15;

  // bijective XCD-aware block swizzle over linear grid
  const int tn_n = N / BN;
  const int nwg = (int)gridDim.x;
  const int q = nwg >> 3, r = nwg & 7;
  const int xcd = (int)blockIdx.x & 7, lin = (int)blockIdx.x >> 3;
  const int wg = (xcd < r) ? xcd * (q + 1) + lin
                           : r * (q + 1) + (xcd - r) * q + lin;
  const int m0 = (wg / tn_n) * 256, n0 = (wg % tn_n) * BN;

  // ---- staging address prep (wave-uniform row blocks, lane part in 1 VGPR)
  const int blk0 = wave * 2, blk1 = blk0 + 1;                 // 8-row blocks
  const int arb0 = ((blk0 & 7) << 3) + ((blk0 >> 3) << 7);    // + mh*64
  const int arb1 = ((blk1 & 7) << 3) + ((blk1 >> 3) << 7);
  int bh0r0, bh0r1, bh1r0, bh1r1;
  if constexpr (BN == 256) {                  // h0 = (r&63)<32, h1 = rest
    bh0r0 = ((blk0 >> 2) << 6) + ((blk0 & 3) << 3);
    bh0r1 = ((blk1 >> 2) << 6) + ((blk1 & 3) << 3);
    bh1r0 = bh0r0 + 32; bh1r1 = bh0r1 + 32;
  } else {                                    // h0 = (r%48)<32 (16 granules), h1 = rest (8)
    bh0r0 = (blk0 >> 2) * 48 + ((blk0 & 3) << 3);
    bh0r1 = (blk1 >> 2) * 48 + ((blk1 & 3) << 3);
    bh1r0 = (wave >> 1) * 48 + 32 + (wave & 1) * 8;
    bh1r1 = 0;                                // unused
  }
  const int lrow = lane >> 3;
  const int loff = lrow * K + (((lane & 7) ^ lrow) << 3);     // lane part (VGPR)
  const unsigned short* Abase = A + (size_t)m0 * K;
  const unsigned short* Bbase = Bt + (size_t)n0 * K;

  // ---- fragment-read bases
  const int pg0 = ((quad) ^ (l16 & 7)) * 8;        // ks=0 granule (elems)
  const int pg1 = ((quad + 4) ^ (l16 & 7)) * 8;    // ks=1 granule
  const int arow = ((wave >> 2) * 128 + l16) * 64;
  const int brow = ((wave & 3) * (BN / 4) + l16) * 64;

  f32x4 acc[8][NF] = {};
  short8 A0[4][2], A1[4][2], Bx[2][2], By[2][2];

  const int nt = K >> 6;
  // ---- prologue: tiles 0 and 1 fully staged; tile0 guaranteed, tile1 in flight
  STG_A(0, 0, 0); STG_BH0(0, 0); STG_BH1(0, 0); STG_A(0, 1, 0);
  STG_A(1, 0, 1); STG_BH0(1, 1); STG_BH1(1, 1); STG_A(1, 1, 1);
  if constexpr (BN == 256) { WAIT_VM(8); } else { WAIT_VM(7); }
  GBAR();
  ISSUE_A0_B0(0, Bx);   // tile 0: A0 + B0 reads in flight

  for (int t = 0; t < nt; t += 2) {
    BODY(t, 0, Bx, By);
    BODY(t + 1, 1, By, Bx);
  }

  // ---- epilogue: acc[mf][nf] -> C
  const int cm = m0 + (wave >> 2) * 128 + quad * 4;
  const int cn = n0 + (wave & 3) * (BN / 4) + l16;
#pragma unroll
  for (int i = 0; i < 8; ++i)
#pragma unroll
    for (int j = 0; j < NF; ++j)
#pragma unroll
      for (int rr = 0; rr < 4; ++rr) {
        const size_t idx = (size_t)(cm + i * 16 + rr) * N + (cn + j * 16);
        if constexpr (sizeof(OutT) == 4) C[idx] = acc[i][j][rr];
        else                             C[idx] = (OutT)f2bf(acc[i][j][rr]);
      }
}

#undef STG_A
#undef STG_BH0
#undef STG_BH1
#undef ISSUE_A0_B0
#undef ISSUE_B1_A1
#undef QMFMA
#undef BODY

// ---------------- RMSNorm + RoPE (Q,K only; V handled by transpose_v) --------
// Q output pre-scaled by QSC = SCALE*log2(e) so softmax runs in exp2 domain.
__global__ __launch_bounds__(256) void rmsnorm_rope_kernel(
    const unsigned short* __restrict__ qkv,
    const float* __restrict__ q_scale, const float* __restrict__ k_scale,
    const float* __restrict__ cosc, const float* __restrict__ sinc,
    unsigned short* __restrict__ qo,   // (B,H,S,DH)
    unsigned short* __restrict__ ko)   // (B,KVH,S,DH)
{
  const int row = blockIdx.x;              // b*S + s
  const int b = row >> 11, s = row & 2047;
  const int tid = threadIdx.x;
  const unsigned short* qr = qkv + (size_t)row * 6144;
  // vectorized sum of squares
  short8 qv0 = *(const short8*)&qr[tid * 8];
  short8 qv1 = *(const short8*)&qr[2048 + tid * 8];
  ushort4 kv = *(const ushort4*)&qr[4096 + tid * 4];
  float sq = 0.f, sk = 0.f;
#pragma unroll
  for (int e = 0; e < 8; e++) {
    float a = bf2f((unsigned short)qv0[e]); sq += a * a;
    float c = bf2f((unsigned short)qv1[e]); sq += c * c;
  }
  float kf[4];
#pragma unroll
  for (int e = 0; e < 4; e++) {
    kf[e] = bf2f(((const unsigned short*)&kv)[e]); sk += kf[e] * kf[e];
  }
#pragma unroll
  for (int off = 32; off; off >>= 1) {
    sq += __shfl_down(sq, off, 64);
    sk += __shfl_down(sk, off, 64);
  }
  __shared__ float redq[4], redk[4];
  if ((tid & 63) == 0) { redq[tid >> 6] = sq; redk[tid >> 6] = sk; }
  __syncthreads();
  sq = redq[0] + redq[1] + redq[2] + redq[3];
  sk = redk[0] + redk[1] + redk[2] + redk[3];
  const float rq = rsqrtf(sq * (1.f / 4096.f) + 1e-6f);
  const float rk = rsqrtf(sk * (1.f / 1024.f) + 1e-6f);
  const float* cp = cosc + (size_t)row * 128;
  const float* sp = sinc + (size_t)row * 128;
  // Q: two chunks of 8 contiguous elems per thread
#pragma unroll
  for (int it = 0; it < 2; it++) {
    const int c = it * 2048 + tid * 8;
    const int d = c & 127, hh = c >> 7;
    short8 v8 = it ? qv1 : qv0;
    short8 p8 = *(const short8*)&qr[c ^ 64];   // rotate-half partner granule
    const float sgn = (d < 64) ? -1.f : 1.f;
    ushort o8[8];
#pragma unroll
    for (int e = 0; e < 8; e++) {
      float v = bf2f((unsigned short)v8[e]) * rq * q_scale[c + e];
      float p = bf2f((unsigned short)p8[e]) * rq * q_scale[(c ^ 64) + e];
      o8[e] = f2bf((v * cp[d + e] + sgn * p * sp[d + e]) * QSC);
    }
    *(uint4*)&qo[((size_t)(b * HH + hh) * SS + s) * DH + d] = *(const uint4*)o8;
  }
  // K: 4 contiguous elems per thread
  {
    const int c = tid * 4;
    const int d = c & 127, hh = c >> 7;
    ushort4 p4 = *(const ushort4*)&qr[4096 + (c ^ 64)];
    const float sgn = (d < 64) ? -1.f : 1.f;
    ushort o4[4];
#pragma unroll
    for (int e = 0; e < 4; e++) {
      float v = kf[e] * rk * k_scale[c + e];
      float p = bf2f(((const unsigned short*)&p4)[e]) * rk * k_scale[(c ^ 64) + e];
      o4[e] = f2bf(v * cp[d + e] + sgn * p * sp[d + e]);
    }
    *(uint2*)&ko[((size_t)(b * KVH + hh) * SS + s) * DH + d] = *(const uint2*)o4;
  }
}

// ---------------- Flash attention: S^T form, 128 q-rows/block, 64-key tiles -----
// Double-buffered K/V (2-phase prefetch): tile t+1's 8 global_load_lds issue
// BEFORE tile t's compute; one __syncthreads per tile (implicit vmcnt(0) drain
// proves t+1 landed AND all waves consumed buf[t&1] -- WAR-safe). s_setprio(1)
// around QK and PV MFMA clusters. LDS 80 KiB -> 2 blocks/CU.
#define STAGE_KV(KT, PB)                                                        \
  _Pragma("unroll") for (int j = 0; j < 4; j++) {                               \
    async16(Kg + (size_t)(KT) * 8192 + bK[j], &Ks[PB][(wave * 4 + j) * 512]);   \
    async16(Vg + (size_t)(KT) * 64 + bV[j], &Vs[PB][(wave * 4 + j) * 512]);     \
  }

__global__ __launch_bounds__(256, 2) void flash_attn(
    const unsigned short* __restrict__ Q,   // (B,H,S,DH), pre-scaled by QSC
    const unsigned short* __restrict__ Kr,  // (B,KVH,S,DH)
    const unsigned short* __restrict__ Vt,  // (B,KVH,DH,S)
    unsigned short* __restrict__ O)         // (B,S,H*DH)
{
  __shared__ __align__(16) unsigned short Ks[2][8192];  // 2x(64 keys x 128 d) swizzled
  __shared__ __align__(16) unsigned short Vs[2][8192];  // 2x(128 d x 64 keys) swizzled
  __shared__ __align__(16) unsigned int   Ps[4][1024];  // per-wave P [32 m][64 k] bf16 (swizzled)
  const int tid = threadIdx.x, wave = tid >> 6, lane = tid & 63;
  const int quad = lane >> 4, l16 = lane & 15;
  const int bh = blockIdx.x, b = bh >> 5, h = bh & 31;
  const int kvh = h >> 2;
  const int qbase = ((int)gridDim.y - 1 - (int)blockIdx.y) * 128;  // heavy-first
  const unsigned short* Qb = Q + (size_t)(b * HH + h) * SS * DH;
  short8 qf[2][4];
#pragma unroll
  for (int mi = 0; mi < 2; mi++) {
    const unsigned short* Qp = Qb + (size_t)(qbase + mi * 64 + wave * 16 + l16) * DH + quad * 8;
#pragma unroll
    for (int c = 0; c < 4; c++) qf[mi][c] = *(const short8*)(Qp + c * 32);
  }
  const unsigned short* Kg = Kr + (size_t)(b * KVH + kvh) * SS * DH;
  const unsigned short* Vg = Vt + (size_t)(b * KVH + kvh) * DH * SS;
  int bK[4], bV[4];
#pragma unroll
  for (int j = 0; j < 4; j++) {
    const int kk = wave * 16 + j * 4 + quad;
    const int gd = l16 ^ ((j * 4 + quad) & 15);
    bK[j] = kk * 128 + gd * 8;
    const int dd = (wave * 4 + j) * 8 + (lane >> 3);
    const int gk = (lane & 7) ^ ((lane >> 3) & 7);
    bV[j] = dd * 2048 + gk * 8;
  }
  f32x4 o[2][8] = {};
  float m_i[2] = {-1e30f, -1e30f}, l_i[2] = {0.f, 0.f};
  const int ndiag = qbase >> 6;
  const int nkt = ndiag + 2;

  STAGE_KV(0, 0);
  __syncthreads();               // implicit vmcnt(0): tile 0 landed
  for (int kt = 0; kt < nkt; kt++) {
    const int pb = kt & 1;
    if (kt + 1 < nkt) { STAGE_KV(kt + 1, pb ^ 1); }   // prefetch under compute
    const unsigned short* Kb = &Ks[pb][0];
    const unsigned short* Vb = &Vs[pb][0];
    const int k0 = kt * 64;
    f32x4 st[4][2] = {};
    __builtin_amdgcn_s_setprio(1);
#pragma unroll
    for (int km = 0; km < 4; km++) {
      const unsigned short* krow = Kb + (km * 16 + l16) * 128;
#pragma unroll
      for (int c = 0; c < 4; c++) {
        short8 kf = *(const short8*)(krow + (((c * 4 + quad) ^ l16) * 8));
        st[km][0] = mfma16(kf, qf[0][c], st[km][0]);
        st[km][1] = mfma16(kf, qf[1][c], st[km][1]);
      }
    }
    __builtin_amdgcn_s_setprio(0);
    const bool mtile = (kt >= ndiag);
    float alpha[2];
#pragma unroll
    for (int mi = 0; mi < 2; mi++) {
      if (mtile) {
        const int qg = qbase + mi * 64 + wave * 16 + l16;
#pragma unroll
        for (int km = 0; km < 4; km++)
#pragma unroll
          for (int r = 0; r < 4; r++)
            if (k0 + km * 16 + quad * 4 + r > qg) st[km][mi][r] = -1e4f;
      }
      float tmax = -3e38f;
#pragma unroll
      for (int km = 0; km < 4; km++)
#pragma unroll
        for (int r = 0; r < 4; r++) tmax = fmaxf(tmax, st[km][mi][r]);
      tmax = fmaxf(tmax, __shfl_xor(tmax, 16, 64));
      tmax = fmaxf(tmax, __shfl_xor(tmax, 32, 64));
      const float mn = fmaxf(m_i[mi], tmax);
      alpha[mi] = __builtin_amdgcn_exp2f(m_i[mi] - mn);
      m_i[mi] = mn;
      float rs = 0.f;
#pragma unroll
      for (int km = 0; km < 4; km++)
#pragma unroll
        for (int r = 0; r < 4; r++) {
          float e = __builtin_amdgcn_exp2f(st[km][mi][r] - mn);
          st[km][mi][r] = e;
          rs += e;
        }
      rs += __shfl_xor(rs, 16, 64);
      rs += __shfl_xor(rs, 32, 64);
      l_i[mi] = l_i[mi] * alpha[mi] + rs;
      unsigned int* pw = &Ps[wave][(mi * 16 + l16) * 32 + (quad & 1) * 2];
#pragma unroll
      for (int km = 0; km < 4; km++) {
        const int g = (km * 2 + (quad >> 1)) ^ (l16 & 7);
        float e0 = st[km][mi][0], e1 = st[km][mi][1], e2 = st[km][mi][2], e3 = st[km][mi][3];
        pw[g * 4]     = __builtin_amdgcn_perm(__builtin_bit_cast(unsigned int, e1),
                                              __builtin_bit_cast(unsigned int, e0), 0x07060302u);
        pw[g * 4 + 1] = __builtin_amdgcn_perm(__builtin_bit_cast(unsigned int, e3),
                                              __builtin_bit_cast(unsigned int, e2), 0x07060302u);
      }
    }
    if (__any((alpha[0] != 1.f) || (alpha[1] != 1.f))) {
#pragma unroll
      for (int mi = 0; mi < 2; mi++) {
        float ar[4];
#pragma unroll
        for (int r = 0; r < 4; r++)
          ar[r] = __shfl(alpha[mi], (lane & 48) + quad * 4 + r, 64);
#pragma unroll
        for (int f = 0; f < 8; f++)
#pragma unroll
          for (int r = 0; r < 4; r++) o[mi][f][r] *= ar[r];
      }
    }
#pragma unroll
    for (int kc = 0; kc < 2; kc++) {
      short8 pa[2];
#pragma unroll
      for (int mi = 0; mi < 2; mi++) {
        const int g = (kc * 4 + quad) ^ (l16 & 7);
        uint4 pv4 = *(const uint4*)&Ps[wave][(mi * 16 + l16) * 32 + g * 4];
        pa[mi] = __builtin_bit_cast(short8, pv4);
      }
      __builtin_amdgcn_s_setprio(1);
#pragma unroll
      for (int f = 0; f < 8; f++) {
        const int d = f * 16 + l16;
        short8 vf = *(const short8*)(Vb + d * 64 + (((kc * 4 + quad) ^ (l16 & 7)) * 8));
        o[0][f] = mfma16(pa[0], vf, o[0][f]);
        o[1][f] = mfma16(pa[1], vf, o[1][f]);
      }
      __builtin_amdgcn_s_setprio(0);
    }
    __syncthreads();             // drains vmcnt (tile kt+1 landed) + rendezvous
  }
  float il[2][4];
#pragma unroll
  for (int mi = 0; mi < 2; mi++)
#pragma unroll
    for (int r = 0; r < 4; r++) {
      float lv = __shfl(l_i[mi], (lane & 48) + quad * 4 + r, 64);
      il[mi][r] = 1.f / lv;
    }
#pragma unroll
  for (int mi = 0; mi < 2; mi++) {
    unsigned short* Op = O + (size_t)(b * SS + qbase + mi * 64 + wave * 16 + quad * 4) * DD + h * DH + l16;
#pragma unroll
    for (int f = 0; f < 8; f++)
#pragma unroll
      for (int r = 0; r < 4; r++)
        Op[(size_t)r * DD + f * 16] = f2bf(o[mi][f][r] * il[mi][r]);
  }
}
#undef STAGE_KV

// -------------------------------------------------------------------------------
extern "C" void kernel_launch(void* const* d_in, const int* in_sizes, int n_in,
                              void* d_out, int out_size, void* d_ws, size_t ws_size,
                              hipStream_t stream) {
  const float* hs      = (const float*)d_in[0];
  const float* wqkv    = (const float*)d_in[1];
  const float* wout    = (const float*)d_in[2];
  const float* q_scale = (const float*)d_in[3];
  const float* k_scale = (const float*)d_in[4];
  const float* cosc    = (const float*)d_in[5];
  const float* sinc    = (const float*)d_in[6];
  // d_in[7] = attention_mask: causal, recomputed from indices — not read.
  float* out = (float*)d_out;

  unsigned short* ws = (unsigned short*)d_ws;
  unsigned short* wqkvT = ws;                        // 6144*4096 = 25165824
  unsigned short* woutT = wqkvT + 25165824;          // 4096*4096 = 16777216
  unsigned short* hsb   = woutT + 16777216;          // 4096*4096 = 16777216
  unsigned short* qkv   = hsb + 16777216;            // 4096*6144 = 25165824
  unsigned short* qrope = wqkvT;                     // alias (wqkvT dead after GEMM1)
  unsigned short* krope = wqkvT + 16777216;
  unsigned short* vT    = wqkvT + 16777216 + 4194304;
  unsigned short* attno = hsb;                       // alias (hsb dead after GEMM1)

  cast_bf16_kernel<<<16384, 256, 0, stream>>>(hs, hsb, 4194304);
  transpose_cast_kernel<<<dim3(192, 128), dim3(32, 8), 0, stream>>>(wqkv, wqkvT, 4096, 6144);
  transpose_cast_kernel<<<dim3(128, 128), dim3(32, 8), 0, stream>>>(wout, woutT, 4096, 4096);
  gemm_bt<192, unsigned short><<<dim3(512), 512, 0, stream>>>(hsb, wqkvT, qkv, 4096, 6144, 4096);
  rmsnorm_rope_kernel<<<4096, 256, 0, stream>>>(qkv, q_scale, k_scale, cosc, sinc,
                                                qrope, krope);
  transpose_v_kernel<<<dim3(64, 4, 16), dim3(32, 8), 0, stream>>>(qkv, vT);
  flash_attn<<<dim3(64, 16), 256, 0, stream>>>(qrope, krope, vT, attno);
  gemm_bt<256, float><<<dim3(256), 512, 0, stream>>>(attno, woutT, out, 4096, 4096, 4096);
}